// Round 7
// baseline (17.519 us; speedup 1.0000x reference)
//
#include <hip/hip_runtime.h>
#include <math.h>

#define H_DIM 1024
#define N_DIM 64
#define L_DIM 2048
#define NT 256
#define SA 72   // A row stride (bf16 elems): 64 + 8 pad
#define ST 72   // B^T row stride: 64 + 8 pad

typedef float  f32x4  __attribute__((ext_vector_type(4)));
typedef short  bf16x8 __attribute__((ext_vector_type(8)));

__device__ __forceinline__ short f2bf(float x) {
    unsigned u = __builtin_bit_cast(unsigned, x);
    u += 0x7FFFu + ((u >> 16) & 1u);          // round-nearest-even
    return (short)(u >> 16);
}
__device__ __forceinline__ float2 cmul(float2 x, float2 y) {
    return make_float2(fmaf(x.x, y.x, -(x.y * y.y)),
                       fmaf(x.x, y.y,  x.y * y.x));
}
__device__ __forceinline__ float2 csq(float2 x) {
    return make_float2(fmaf(x.x, x.x, -(x.y * x.y)), 2.0f * x.x * x.y);
}

// K[h][32*l1 + l0] = sum_n ( Re(U)[n][l1]*Re(V)[n][l0] - Im(U)[n][l1]*Im(V)[n][l0] )
//   U[n][l1] = w_n * (a_n^32)^l1   (A: M=64 rows l1, K=64 cols n)   [l1][n] in LDS
//   V[n][l0] = a_n^l0              (B: K=64 rows n, N=32 cols l0)   stored TRANSPOSED
//                                  as B_T[l0][n] so fragments are ds_read_b128.
// One block per h; 256 threads = (n, q). A_im stored negated.
__global__ __launch_bounds__(NT, 4)
void lssl_mfma(const float* __restrict__ Lre, const float* __restrict__ Lim,
               const float* __restrict__ Bre, const float* __restrict__ Bim,
               const float* __restrict__ Cre, const float* __restrict__ Cim,
               const float* __restrict__ Dv,  const float* __restrict__ log_dt,
               float* __restrict__ out)
{
    __shared__ __align__(16) short sAre[64 * SA];   // [l1][n]
    __shared__ __align__(16) short sAim[64 * SA];   // negated Im(U)
    __shared__ __align__(16) short sBTre[32 * ST];  // [l0][n]
    __shared__ __align__(16) short sBTim[32 * ST];

    const int h = blockIdx.x;
    const int t = threadIdx.x;
    const int n = t & 63;
    const int q = t >> 6;          // 0..3, wave-uniform

    // ---- per-(h,n) params ----
    const int   idx = h * N_DIM + n;
    const float dt  = expf(log_dt[h]);
    const float lre = Lre[idx];
    const float lim = Lim[idx];
    const float sp  = log1pf(expf(lre));     // softplus
    const float hr  = -0.5f * dt * sp;
    const float hi  =  0.5f * dt * lim;
    const float dr  = 1.0f - hr;             // denom = (dr, -hi)
    const float inv = 1.0f / (dr * dr + hi * hi);
    const float xr  = 1.0f + hr;
    float2 a  = make_float2((xr * dr - hi * hi) * inv, 2.0f * hi * inv); // a_bar
    const float tr  = dt * dr * inv;
    const float ti  = dt * hi * inv;
    const float br  = tr * Bre[idx] - ti * Bim[idx];   // b_bar
    const float bi  = tr * Bim[idx] + ti * Bre[idx];
    const float cre = Cre[idx], cim = Cim[idx];
    float2 w  = make_float2(cre * br - cim * bi,       // w = C*b_bar
                            cre * bi + cim * br);

    // ---- powers by squaring ----
    const float2 a2   = csq(a);
    const float2 a4   = csq(a2);
    const float2 a8   = csq(a4);
    const float2 a16  = csq(a8);
    const float2 a32  = csq(a16);
    const float2 a64  = csq(a32);
    const float2 a128 = csq(a64);
    const float2 a256 = csq(a128);
    const float2 a512 = csq(a256);

    // ---- U chain: l1 = 16q..16q+15, U = w * a^(32*l1) ----
    float2 s = w;
    for (int k = 0; k < q; ++k) s = cmul(s, a512);   // w * a^(512q)
#pragma unroll
    for (int j = 0; j < 16; ++j) {
        const int l1 = 16 * q + j;
        sAre[l1 * SA + n] = f2bf(s.x);
        sAim[l1 * SA + n] = f2bf(-s.y);
        s = cmul(s, a32);
    }

    // ---- V chain: l0 = 8q..8q+7, V = a^l0, written to B_T[l0][n] ----
    float2 v = make_float2(1.0f, 0.0f);
    for (int k = 0; k < q; ++k) v = cmul(v, a8);     // a^(8q)
#pragma unroll
    for (int i = 0; i < 8; ++i) {
        const int l0 = 8 * q + i;
        sBTre[l0 * ST + n] = f2bf(v.x);
        sBTim[l0 * ST + n] = f2bf(v.y);
        v = cmul(v, a);
    }

    __syncthreads();

    // ---- MFMA: wave q owns M-tile q (l1 rows 16q..16q+15) ----
    const int col = t & 15;
    const int grp = (t & 63) >> 4;
    f32x4 acc0 = {0.f, 0.f, 0.f, 0.f};
    f32x4 acc1 = {0.f, 0.f, 0.f, 0.f};

#pragma unroll
    for (int kt = 0; kt < 2; ++kt) {
        const int kbase = kt * 32 + grp * 8;          // k-hat bijection: kt*32+8g+j
        const bf16x8 afr = *(const bf16x8*)&sAre[(q * 16 + col) * SA + kbase];
        const bf16x8 afi = *(const bf16x8*)&sAim[(q * 16 + col) * SA + kbase];
        const bf16x8 b0r = *(const bf16x8*)&sBTre[col * ST + kbase];
        const bf16x8 b0i = *(const bf16x8*)&sBTim[col * ST + kbase];
        const bf16x8 b1r = *(const bf16x8*)&sBTre[(col + 16) * ST + kbase];
        const bf16x8 b1i = *(const bf16x8*)&sBTim[(col + 16) * ST + kbase];
        acc0 = __builtin_amdgcn_mfma_f32_16x16x32_bf16(afr, b0r, acc0, 0, 0, 0);
        acc0 = __builtin_amdgcn_mfma_f32_16x16x32_bf16(afi, b0i, acc0, 0, 0, 0);
        acc1 = __builtin_amdgcn_mfma_f32_16x16x32_bf16(afr, b1r, acc1, 0, 0, 0);
        acc1 = __builtin_amdgcn_mfma_f32_16x16x32_bf16(afi, b1i, acc1, 0, 0, 0);
    }

    // ---- store: D row=(lane>>4)*4+reg, col=lane&15 (measured C/D layout) ----
    float* o = out + (size_t)h * L_DIM;
#pragma unroll
    for (int r = 0; r < 4; ++r) {
        const int row = q * 16 + grp * 4 + r;         // l1
        o[row * 32 + col]      = acc0[r];
        o[row * 32 + 16 + col] = acc1[r];
    }

    if (t == 0) out[(size_t)H_DIM * L_DIM + h] = Dv[h];
}

extern "C" void kernel_launch(void* const* d_in, const int* in_sizes, int n_in,
                              void* d_out, int out_size, void* d_ws, size_t ws_size,
                              hipStream_t stream) {
    const float* Lre   = (const float*)d_in[0];
    const float* Lim   = (const float*)d_in[1];
    const float* Bre   = (const float*)d_in[2];
    const float* Bim   = (const float*)d_in[3];
    const float* Cre   = (const float*)d_in[4];
    const float* Cim   = (const float*)d_in[5];
    const float* Dv    = (const float*)d_in[6];
    const float* logdt = (const float*)d_in[7];
    float* out = (float*)d_out;

    lssl_mfma<<<dim3(H_DIM), dim3(NT), 0, stream>>>(
        Lre, Lim, Bre, Bim, Cre, Cim, Dv, logdt, out);
}

// Round 9
// 11.211 us; speedup vs baseline: 1.5626x; 1.5626x over previous
//
#include <hip/hip_runtime.h>
#include <math.h>

#define H_DIM 1024
#define N_DIM 64
#define L_DIM 2048
#define NT 256
#define SA 72   // A row stride (bf16 elems): 64 + 8 pad

typedef float  f32x4  __attribute__((ext_vector_type(4)));
typedef short  bf16x8 __attribute__((ext_vector_type(8)));

__device__ __forceinline__ short f2bf(float x) {
    unsigned u = __builtin_bit_cast(unsigned, x);
    u += 0x7FFFu + ((u >> 16) & 1u);          // round-nearest-even
    return (short)(u >> 16);
}
__device__ __forceinline__ float2 cmul(float2 x, float2 y) {
    return make_float2(fmaf(x.x, y.x, -(x.y * y.y)),
                       fmaf(x.x, y.y,  x.y * y.x));
}
__device__ __forceinline__ float2 csq(float2 x) {
    return make_float2(fmaf(x.x, x.x, -(x.y * x.y)), 2.0f * x.x * x.y);
}

// K[h][32*l1 + l0] = sum_n ( Re(U)[n][l1]*Re(V)[n][l0] - Im(U)[n][l1]*Im(V)[n][l0] )
//   U[n][l1] = w_n * (a_n^32)^l1   (A: M=64 rows l1, K=64 cols n)  [l1][n] rows in LDS
//   V[n][l0] = a_n^l0              (B: K=64 rows n, N=32 cols l0)  stored in MFMA
//     FRAGMENT layout: idx = (n>>3)*256 + l0*8 + (n&7)  (bijective onto 64*32).
//     Lane (grp,col) of tile kt reads b0 at (kt*4+grp)*256 + col*8 (one contiguous
//     16B slot; element j -> n = kt*32+grp*8+j, matching A's k-hat), and b1 at
//     +128 (= l0 col+16, same n-group). No cross-row b128 striding (round-7 poison).
// One block per h; 256 threads = (n, q). A_im stored negated.
__global__ __launch_bounds__(NT, 4)
void lssl_mfma(const float* __restrict__ Lre, const float* __restrict__ Lim,
               const float* __restrict__ Bre, const float* __restrict__ Bim,
               const float* __restrict__ Cre, const float* __restrict__ Cim,
               const float* __restrict__ Dv,  const float* __restrict__ log_dt,
               float* __restrict__ out)
{
    __shared__ __align__(16) short sAre[64 * SA];   // [l1][n]
    __shared__ __align__(16) short sAim[64 * SA];   // negated Im(U)
    __shared__ __align__(16) short sVfr[64 * 32];   // V re, fragment layout (4KB)
    __shared__ __align__(16) short sVfi[64 * 32];   // V im, fragment layout

    const int h = blockIdx.x;
    const int t = threadIdx.x;
    const int n = t & 63;
    const int q = t >> 6;          // 0..3, wave-uniform

    // ---- per-(h,n) params ----
    const int   idx = h * N_DIM + n;
    const float dt  = expf(log_dt[h]);
    const float lre = Lre[idx];
    const float lim = Lim[idx];
    const float sp  = log1pf(expf(lre));     // softplus
    const float hr  = -0.5f * dt * sp;
    const float hi  =  0.5f * dt * lim;
    const float dr  = 1.0f - hr;             // denom = (dr, -hi)
    const float inv = 1.0f / (dr * dr + hi * hi);
    const float xr  = 1.0f + hr;
    float2 a  = make_float2((xr * dr - hi * hi) * inv, 2.0f * hi * inv); // a_bar
    const float tr  = dt * dr * inv;
    const float ti  = dt * hi * inv;
    const float br  = tr * Bre[idx] - ti * Bim[idx];   // b_bar
    const float bi  = tr * Bim[idx] + ti * Bre[idx];
    const float cre = Cre[idx], cim = Cim[idx];
    float2 w  = make_float2(cre * br - cim * bi,       // w = C*b_bar
                            cre * bi + cim * br);

    // ---- powers by squaring ----
    const float2 a2   = csq(a);
    const float2 a4   = csq(a2);
    const float2 a8   = csq(a4);
    const float2 a16  = csq(a8);
    const float2 a32  = csq(a16);
    const float2 a64  = csq(a32);
    const float2 a128 = csq(a64);
    const float2 a256 = csq(a128);
    const float2 a512 = csq(a256);

    // ---- U chain: l1 = 16q..16q+15, U = w * a^(32*l1) ----
    float2 s = w;
    for (int k = 0; k < q; ++k) s = cmul(s, a512);   // w * a^(512q)
#pragma unroll
    for (int j = 0; j < 16; ++j) {
        const int l1 = 16 * q + j;
        sAre[l1 * SA + n] = f2bf(s.x);
        sAim[l1 * SA + n] = f2bf(-s.y);
        s = cmul(s, a32);
    }

    // ---- V chain: l0 = 8q..8q+7, V = a^l0, written in fragment layout ----
    const int vbase = (n >> 3) * 256 + (n & 7);
    float2 v = make_float2(1.0f, 0.0f);
    for (int k = 0; k < q; ++k) v = cmul(v, a8);     // a^(8q)
#pragma unroll
    for (int i = 0; i < 8; ++i) {
        const int l0 = 8 * q + i;
        sVfr[vbase + l0 * 8] = f2bf(v.x);
        sVfi[vbase + l0 * 8] = f2bf(v.y);
        v = cmul(v, a);
    }

    __syncthreads();

    // ---- MFMA: wave q owns M-tile q (l1 rows 16q..16q+15) ----
    const int col = t & 15;
    const int grp = (t & 63) >> 4;
    f32x4 acc0 = {0.f, 0.f, 0.f, 0.f};
    f32x4 acc1 = {0.f, 0.f, 0.f, 0.f};

#pragma unroll
    for (int kt = 0; kt < 2; ++kt) {
        const int kbase = kt * 32 + grp * 8;          // k-hat bijection: kt*32+8g+j
        const bf16x8 afr = *(const bf16x8*)&sAre[(q * 16 + col) * SA + kbase];
        const bf16x8 afi = *(const bf16x8*)&sAim[(q * 16 + col) * SA + kbase];
        // B-frag base: (kt*4+grp)*256 + col*8 (contiguous 16B per lane);
        // +128 elems = l0 col+16, same n-group.
        const int fb0 = (kt * 4 + grp) * 256 + col * 8;
        const bf16x8 b0r = *(const bf16x8*)&sVfr[fb0];
        const bf16x8 b0i = *(const bf16x8*)&sVfi[fb0];
        const bf16x8 b1r = *(const bf16x8*)&sVfr[fb0 + 128];
        const bf16x8 b1i = *(const bf16x8*)&sVfi[fb0 + 128];
        acc0 = __builtin_amdgcn_mfma_f32_16x16x32_bf16(afr, b0r, acc0, 0, 0, 0);
        acc0 = __builtin_amdgcn_mfma_f32_16x16x32_bf16(afi, b0i, acc0, 0, 0, 0);
        acc1 = __builtin_amdgcn_mfma_f32_16x16x32_bf16(afr, b1r, acc1, 0, 0, 0);
        acc1 = __builtin_amdgcn_mfma_f32_16x16x32_bf16(afi, b1i, acc1, 0, 0, 0);
    }

    // ---- store: D row=(lane>>4)*4+reg, col=lane&15 (measured C/D layout) ----
    float* o = out + (size_t)h * L_DIM;
#pragma unroll
    for (int r = 0; r < 4; ++r) {
        const int row = q * 16 + grp * 4 + r;         // l1
        o[row * 32 + col]      = acc0[r];
        o[row * 32 + 16 + col] = acc1[r];
    }

    if (t == 0) out[(size_t)H_DIM * L_DIM + h] = Dv[h];
}

extern "C" void kernel_launch(void* const* d_in, const int* in_sizes, int n_in,
                              void* d_out, int out_size, void* d_ws, size_t ws_size,
                              hipStream_t stream) {
    const float* Lre   = (const float*)d_in[0];
    const float* Lim   = (const float*)d_in[1];
    const float* Bre   = (const float*)d_in[2];
    const float* Bim   = (const float*)d_in[3];
    const float* Cre   = (const float*)d_in[4];
    const float* Cim   = (const float*)d_in[5];
    const float* Dv    = (const float*)d_in[6];
    const float* logdt = (const float*)d_in[7];
    float* out = (float*)d_out;

    lssl_mfma<<<dim3(H_DIM), dim3(NT), 0, stream>>>(
        Lre, Lim, Bre, Bim, Cre, Cim, Dv, logdt, out);
}

// Round 10
// 10.228 us; speedup vs baseline: 1.7128x; 1.0961x over previous
//
#include <hip/hip_runtime.h>
#include <math.h>

#define H_DIM 1024
#define N_DIM 64
#define L_DIM 2048
#define NT 256
#define SAU 68   // A' row stride in uints: 64 + 4 pad  (=136 bf16, 272B)

typedef float    f32x4  __attribute__((ext_vector_type(4)));
typedef short    bf16x8 __attribute__((ext_vector_type(8)));

__device__ __forceinline__ float exp2_hw(float x) {
    float o; asm("v_exp_f32 %0, %1" : "=v"(o) : "v"(x)); return o;
}
__device__ __forceinline__ float log2_hw(float x) {
    float o; asm("v_log_f32 %0, %1" : "=v"(o) : "v"(x)); return o;
}
// packs (lo, hi) -> one u32 of two bf16 (lo in low 16)
__device__ __forceinline__ unsigned cvt_pk_bf16(float lo, float hi) {
    unsigned r; asm("v_cvt_pk_bf16_f32 %0, %1, %2" : "=v"(r) : "v"(lo), "v"(hi));
    return r;
}
__device__ __forceinline__ float2 cmul(float2 x, float2 y) {
    return make_float2(fmaf(x.x, y.x, -(x.y * y.y)),
                       fmaf(x.x, y.y,  x.y * y.x));
}
__device__ __forceinline__ float2 csq(float2 x) {
    return make_float2(fmaf(x.x, x.x, -(x.y * x.y)), 2.0f * x.x * x.y);
}

// K[h][32*l1+l0] = sum_k A'[l1][k] * B'[k][l0]  over k = 0..127, where
//   A'[l1][2n] = Re(U)[n][l1],  A'[l1][2n+1] = -Im(U)[n][l1]   (U = w * a^(32 l1))
//   B'[2n][l0] = Re(V)[n][l0],  B'[2n+1][l0] =  Im(V)[n][l0]   (V = a^l0)
// so each complex value-pair is ONE cvt_pk_bf16 + ONE ds_write_b32.
// A' stored row-major [l1][k] (uint index l1*68 + n). B' stored in MFMA fragment
// slots: slot(g = k>>3, l0) at uint index (g*32 + (l0 ^ (g&7)))*4 + ((k&7)>>1);
// the XOR spreads V's column-writes across all 32 banks (2-way, free), and reads
// stay one contiguous 16B slot per lane (same XOR on both sides).
__global__ __launch_bounds__(NT, 4)
void lssl_mfma(const float* __restrict__ Lre, const float* __restrict__ Lim,
               const float* __restrict__ Bre, const float* __restrict__ Bim,
               const float* __restrict__ Cre, const float* __restrict__ Cim,
               const float* __restrict__ Dv,  const float* __restrict__ log_dt,
               float* __restrict__ out)
{
    __shared__ __align__(16) unsigned sAp[64 * SAU];  // A' (17.4 KB)
    __shared__ __align__(16) unsigned sBp[16 * 32 * 4]; // B' (8 KB)

    const int h = blockIdx.x;
    const int t = threadIdx.x;
    const int n = t & 63;
    const int q = t >> 6;          // 0..3, wave-uniform

    // ---- per-(h,n) params (hw transcendentals; lre in [0,1], log_dt in [-6.9,-2.3]) ----
    const float LOG2E = 1.44269504089f, LN2 = 0.69314718056f;
    const int   idx = h * N_DIM + n;
    const float dt  = exp2_hw(log_dt[h] * LOG2E);
    const float lre = Lre[idx];
    const float lim = Lim[idx];
    const float sp  = LN2 * log2_hw(1.0f + exp2_hw(lre * LOG2E));  // softplus
    const float hr  = -0.5f * dt * sp;
    const float hi  =  0.5f * dt * lim;
    const float dr  = 1.0f - hr;             // denom = (dr, -hi)
    const float inv = 1.0f / (dr * dr + hi * hi);
    const float xr  = 1.0f + hr;
    float2 a  = make_float2((xr * dr - hi * hi) * inv, 2.0f * hi * inv); // a_bar
    const float tr  = dt * dr * inv;
    const float ti  = dt * hi * inv;
    const float br  = tr * Bre[idx] - ti * Bim[idx];   // b_bar
    const float bi  = tr * Bim[idx] + ti * Bre[idx];
    const float cre = Cre[idx], cim = Cim[idx];
    float2 w  = make_float2(cre * br - cim * bi,       // w = C*b_bar
                            cre * bi + cim * br);

    // ---- powers by squaring ----
    const float2 a2   = csq(a);
    const float2 a4   = csq(a2);
    const float2 a8   = csq(a4);
    const float2 a16  = csq(a8);
    const float2 a32  = csq(a16);
    const float2 a64  = csq(a32);
    const float2 a128 = csq(a64);
    const float2 a256 = csq(a128);
    const float2 a512 = csq(a256);

    // ---- U chain: l1 = 16q..16q+15, U = w * a^(32*l1); store (re, -im) packed ----
    float2 s = w;
    for (int k = 0; k < q; ++k) s = cmul(s, a512);   // w * a^(512q)
#pragma unroll
    for (int j = 0; j < 16; ++j) {
        const int l1 = 16 * q + j;
        const float nim = -s.y;
        sAp[l1 * SAU + n] = cvt_pk_bf16(s.x, nim);
        s = cmul(s, a32);
    }

    // ---- V chain: l0 = 8q..8q+7, V = a^l0; store (re, im) packed in swizzled slot ----
    const int g   = n >> 2;        // k-group = (2n)>>3
    const int gs4 = (g & 7) << 2;  // swizzle, pre-shifted to uint units
    const int vb  = g * 128 + 32 * q + (n & 3);
    float2 v = make_float2(1.0f, 0.0f);
    for (int k = 0; k < q; ++k) v = cmul(v, a8);     // a^(8q)
#pragma unroll
    for (int i = 0; i < 8; ++i) {
        sBp[vb + ((i << 2) ^ gs4)] = cvt_pk_bf16(v.x, v.y);
        v = cmul(v, a);
    }

    __syncthreads();

    // ---- MFMA: wave q owns M-tile q; K=128 in 4 steps of 32 ----
    const int col = t & 15;
    const int grp = (t & 63) >> 4;
    f32x4 acc0 = {0.f, 0.f, 0.f, 0.f};
    f32x4 acc1 = {0.f, 0.f, 0.f, 0.f};

#pragma unroll
    for (int ks = 0; ks < 4; ++ks) {
        const int gg  = ks * 4 + grp;                 // k-hat: gg*8 + j
        const bf16x8 af = *(const bf16x8*)&sAp[(q * 16 + col) * SAU + ks * 16 + grp * 4];
        const int b0i = (gg * 32 + (col ^ (gg & 7))) * 4;
        const bf16x8 b0 = *(const bf16x8*)&sBp[b0i];
        const bf16x8 b1 = *(const bf16x8*)&sBp[b0i + 64];   // l0 = col+16 (xor preserves +16)
        acc0 = __builtin_amdgcn_mfma_f32_16x16x32_bf16(af, b0, acc0, 0, 0, 0);
        acc1 = __builtin_amdgcn_mfma_f32_16x16x32_bf16(af, b1, acc1, 0, 0, 0);
    }

    // ---- store: D row=(lane>>4)*4+reg, col=lane&15 (measured C/D layout) ----
    float* o = out + (size_t)h * L_DIM;
#pragma unroll
    for (int r = 0; r < 4; ++r) {
        const int row = q * 16 + grp * 4 + r;         // l1
        o[row * 32 + col]      = acc0[r];
        o[row * 32 + 16 + col] = acc1[r];
    }

    if (t == 0) out[(size_t)H_DIM * L_DIM + h] = Dv[h];
}

extern "C" void kernel_launch(void* const* d_in, const int* in_sizes, int n_in,
                              void* d_out, int out_size, void* d_ws, size_t ws_size,
                              hipStream_t stream) {
    const float* Lre   = (const float*)d_in[0];
    const float* Lim   = (const float*)d_in[1];
    const float* Bre   = (const float*)d_in[2];
    const float* Bim   = (const float*)d_in[3];
    const float* Cre   = (const float*)d_in[4];
    const float* Cim   = (const float*)d_in[5];
    const float* Dv    = (const float*)d_in[6];
    const float* logdt = (const float*)d_in[7];
    float* out = (float*)d_out;

    lssl_mfma<<<dim3(H_DIM), dim3(NT), 0, stream>>>(
        Lre, Lim, Bre, Bim, Cre, Cim, Dv, logdt, out);
}